// Round 1
// baseline (222.700 us; speedup 1.0000x reference)
//
#include <hip/hip_runtime.h>
#include <math.h>

// Problem dims (fixed by reference)
#define BATCH 2048
#define GIN 128
#define GH 128
#define NE 8
#define XIN 512
#define UU 512
#define NOUT 512
#define KAUG (NE * XIN)   // 4096
#define SPLIT 8
#define KS (KAUG / SPLIT) // 512 per k-split block

typedef __attribute__((ext_vector_type(8))) short short8;   // 8 bf16 in 4 VGPRs
typedef __attribute__((ext_vector_type(4))) float f32x4;

__device__ inline unsigned short f2bf(float f) {
    // round-to-nearest-even fp32 -> bf16 (values are well-behaved, no NaN path)
    unsigned u = __float_as_uint(f);
    u += 0x7fffu + ((u >> 16) & 1u);
    return (unsigned short)(u >> 16);
}

__device__ inline float elu1(float x) { return x > 0.f ? x : (expf(x) - 1.f); }

// ---------------------------------------------------------------------------
// Gating MLP: fp32 exact. 16 rows per block, 128 threads (thread = out feature).
// ---------------------------------------------------------------------------
__global__ __launch_bounds__(128) void gating_kernel(
    const float* __restrict__ gin, const float* __restrict__ W0, const float* __restrict__ b0,
    const float* __restrict__ W1, const float* __restrict__ b1,
    const float* __restrict__ Wo, const float* __restrict__ bo,
    float* __restrict__ g)
{
    __shared__ float xs[16][128];
    __shared__ float hs[16][128];
    __shared__ float ls[16][8];
    const int t = threadIdx.x;
    const int row0 = blockIdx.x * 16;

    for (int r = 0; r < 16; ++r) xs[r][t] = gin[(row0 + r) * GIN + t];
    __syncthreads();

    float acc[16];
    #pragma unroll
    for (int r = 0; r < 16; ++r) acc[r] = 0.f;
    for (int i = 0; i < GIN; ++i) {
        float w = W0[i * GH + t];
        #pragma unroll
        for (int r = 0; r < 16; ++r) acc[r] += xs[r][i] * w;
    }
    {
        float bb = b0[t];
        for (int r = 0; r < 16; ++r) hs[r][t] = elu1(acc[r] + bb);
    }
    __syncthreads();

    #pragma unroll
    for (int r = 0; r < 16; ++r) acc[r] = 0.f;
    for (int i = 0; i < GH; ++i) {
        float w = W1[i * GH + t];
        #pragma unroll
        for (int r = 0; r < 16; ++r) acc[r] += hs[r][i] * w;
    }
    {
        float bb = b1[t];
        for (int r = 0; r < 16; ++r) xs[r][t] = elu1(acc[r] + bb);
    }
    __syncthreads();

    {   // output layer: thread t -> (row r = t>>3, expert e = t&7)
        int r = t >> 3, e = t & 7;
        float lg = bo[e];
        for (int i = 0; i < GH; ++i) lg += xs[r][i] * Wo[i * NE + e];
        ls[r][e] = lg;
    }
    __syncthreads();
    if (t < 16) {
        float mx = ls[t][0];
        #pragma unroll
        for (int e = 1; e < 8; ++e) mx = fmaxf(mx, ls[t][e]);
        float s = 0.f, ex[8];
        #pragma unroll
        for (int e = 0; e < 8; ++e) { ex[e] = expf(ls[t][e] - mx); s += ex[e]; }
        float inv = 1.f / s;
        #pragma unroll
        for (int e = 0; e < 8; ++e) g[(row0 + t) * NE + e] = ex[e] * inv;
    }
}

// ---------------------------------------------------------------------------
// Convert the three alpha pools fp32 -> bf16 (contiguous in ws). 4 elems/thread.
// ---------------------------------------------------------------------------
__global__ __launch_bounds__(256) void convert_alpha_kernel(
    const float* __restrict__ a0, const float* __restrict__ a1, const float* __restrict__ a2,
    unsigned short* __restrict__ ab)
{
    const long long vi = (long long)(blockIdx.x * blockDim.x + threadIdx.x) * 4;
    const int a = (int)(vi >> 21);               // each alpha is 2^21 elements
    const int off = (int)(vi & ((1 << 21) - 1));
    const float* src = (a == 0) ? a0 : ((a == 1) ? a1 : a2);
    float4 v = *(const float4*)(src + off);
    union { unsigned short us[4]; uint2 u2; } p;
    p.us[0] = f2bf(v.x); p.us[1] = f2bf(v.y); p.us[2] = f2bf(v.z); p.us[3] = f2bf(v.w);
    *(uint2*)(ab + vi) = p.u2;
}

// ---------------------------------------------------------------------------
// Build augmented input Z[b, e*512+i] = bf16(g[b,e] * x[b,i]) for layer 1.
// ---------------------------------------------------------------------------
__global__ __launch_bounds__(256) void zbuild0_kernel(
    const float* __restrict__ x, const float* __restrict__ g, unsigned short* __restrict__ Z)
{
    const int gid = blockIdx.x * blockDim.x + threadIdx.x; // b*512 + i
    const int b = gid >> 9, i = gid & 511;
    const float xv = x[gid];
    const float* gb = g + b * NE;
    unsigned short* zr = Z + (size_t)b * KAUG + i;
    #pragma unroll
    for (int e = 0; e < NE; ++e) zr[e * XIN] = f2bf(gb[e] * xv);
}

// ---------------------------------------------------------------------------
// m97-style bf16 GEMM, 128x128 tile, BK=64, k-split over blockIdx.z.
// A: M x K bf16 (Z).  Bw: alpha_bf layout [e][n][i] == B^T rows per 512-col e-block.
// Cp: SPLIT x M x N fp32 partials.
// ---------------------------------------------------------------------------
__global__ __launch_bounds__(256) void gemm_kernel(
    const unsigned short* __restrict__ A,
    const unsigned short* __restrict__ Bw,
    float* __restrict__ Cp)
{
    constexpr int M = BATCH, N = UU, K = KAUG;
    __shared__ unsigned short As[128 * 64];
    __shared__ unsigned short Bs[128 * 64];
    const int t = threadIdx.x;
    const int n0 = blockIdx.x * 128;
    const int m0 = blockIdx.y * 128;
    const int kb = blockIdx.z * KS;
    const int wave = t >> 6, lane = t & 63;
    const int wm = (wave >> 1) * 64, wn = (wave & 1) * 64;

    f32x4 acc[4][4] = {};

    const int trow = t >> 3;        // 0..31
    const int tcol = (t & 7) * 8;   // element col within BK

    for (int k0 = kb; k0 < kb + KS; k0 += 64) {
        __syncthreads();
        const int e = k0 >> 9;
        const int ki = k0 & 511;
        #pragma unroll
        for (int it = 0; it < 4; ++it) {
            const unsigned short* ga = A + (size_t)(m0 + trow + it * 32) * K + k0 + tcol;
            __builtin_amdgcn_global_load_lds(
                (const __attribute__((address_space(1))) void*)ga,
                (__attribute__((address_space(3))) void*)(As + it * 2048 + t * 8), 16, 0, 0);
            const unsigned short* gb = Bw + ((size_t)e * N + (n0 + trow + it * 32)) * 512 + ki + tcol;
            __builtin_amdgcn_global_load_lds(
                (const __attribute__((address_space(1))) void*)gb,
                (__attribute__((address_space(3))) void*)(Bs + it * 2048 + t * 8), 16, 0, 0);
        }
        __syncthreads();

        #pragma unroll
        for (int kk = 0; kk < 64; kk += 32) {
            short8 af[4], bfr[4];
            const int fr = lane & 15;
            const int fk = kk + (lane >> 4) * 8;
            #pragma unroll
            for (int i = 0; i < 4; ++i) af[i] = *(const short8*)(As + (wm + fr + i * 16) * 64 + fk);
            #pragma unroll
            for (int j = 0; j < 4; ++j) bfr[j] = *(const short8*)(Bs + (wn + fr + j * 16) * 64 + fk);
            #pragma unroll
            for (int i = 0; i < 4; ++i)
                #pragma unroll
                for (int j = 0; j < 4; ++j)
                    acc[i][j] = __builtin_amdgcn_mfma_f32_16x16x32_bf16(af[i], bfr[j], acc[i][j], 0, 0, 0);
        }
    }

    // epilogue: C/D mapping col=lane&15, row=(lane>>4)*4+reg  [m89-verified]
    float* Cb = Cp + (size_t)blockIdx.z * M * N;
    const int cl = lane & 15, rq = lane >> 4;
    #pragma unroll
    for (int i = 0; i < 4; ++i)
        #pragma unroll
        for (int j = 0; j < 4; ++j)
            #pragma unroll
            for (int r = 0; r < 4; ++r) {
                int row = m0 + wm + i * 16 + rq * 4 + r;
                int col = n0 + wn + j * 16 + cl;
                Cb[(size_t)row * N + col] = acc[i][j][r];
            }
}

// ---------------------------------------------------------------------------
// Reduce k-split partials + bias blend + ELU; emit next layer's Z (bf16) or
// final output (fp32).
// ---------------------------------------------------------------------------
__global__ __launch_bounds__(256) void reduce_kernel(
    const float* __restrict__ Cp, const float* __restrict__ g,
    const float* __restrict__ beta, unsigned short* __restrict__ Znext,
    float* __restrict__ out, int last)
{
    const int gid = blockIdx.x * blockDim.x + threadIdx.x; // b*512 + u
    const int b = gid >> 9, u = gid & 511;
    float v = 0.f;
    #pragma unroll
    for (int s = 0; s < SPLIT; ++s) v += Cp[(size_t)s * (BATCH * (size_t)UU) + gid];
    const float* gb = g + b * NE;
    float gv[NE];
    #pragma unroll
    for (int e = 0; e < NE; ++e) gv[e] = gb[e];
    #pragma unroll
    for (int e = 0; e < NE; ++e) v += gv[e] * beta[e * UU + u];
    if (last) {
        out[gid] = v;
    } else {
        v = elu1(v);
        unsigned short* zr = Znext + (size_t)b * KAUG + u;
        #pragma unroll
        for (int e = 0; e < NE; ++e) zr[e * UU] = f2bf(gv[e] * v);
    }
}

// ---------------------------------------------------------------------------
extern "C" void kernel_launch(void* const* d_in, const int* in_sizes, int n_in,
                              void* d_out, int out_size, void* d_ws, size_t ws_size,
                              hipStream_t stream)
{
    (void)in_sizes; (void)n_in; (void)out_size; (void)ws_size;
    const float* gin = (const float*)d_in[0];
    const float* xin = (const float*)d_in[1];
    const float* W0  = (const float*)d_in[2];
    const float* b0  = (const float*)d_in[3];
    const float* W1  = (const float*)d_in[4];
    const float* b1  = (const float*)d_in[5];
    const float* Wo  = (const float*)d_in[6];
    const float* bo  = (const float*)d_in[7];
    const float* alpha[3] = {(const float*)d_in[8],  (const float*)d_in[10], (const float*)d_in[12]};
    const float* beta[3]  = {(const float*)d_in[9],  (const float*)d_in[11], (const float*)d_in[13]};
    float* out = (float*)d_out;

    // ws layout (total ~63 MB)
    char* ws = (char*)d_ws;
    float* g = (float*)ws;                                   // 2048*8*4      = 64 KB
    size_t off = 65536;
    unsigned short* ab = (unsigned short*)(ws + off);        // 3 * 2^21 * 2  = 12.58 MB
    off += (size_t)3 * (1 << 21) * 2;
    unsigned short* Z = (unsigned short*)(ws + off);         // 2048*4096*2   = 16.78 MB
    off += (size_t)BATCH * KAUG * 2;
    float* Cp = (float*)(ws + off);                          // 8 * 2048*512*4 = 33.55 MB

    gating_kernel<<<BATCH / 16, 128, 0, stream>>>(gin, W0, b0, W1, b1, Wo, bo, g);
    convert_alpha_kernel<<<(3 * (1 << 21)) / 4 / 256, 256, 0, stream>>>(alpha[0], alpha[1], alpha[2], ab);
    zbuild0_kernel<<<(BATCH * XIN) / 256, 256, 0, stream>>>(xin, g, Z);

    for (int l = 0; l < 3; ++l) {
        gemm_kernel<<<dim3(UU / 128, BATCH / 128, SPLIT), 256, 0, stream>>>(
            Z, ab + (size_t)l * (1 << 21), Cp);
        reduce_kernel<<<(BATCH * UU) / 256, 256, 0, stream>>>(
            Cp, g, beta[l], Z, out, l == 2 ? 1 : 0);
    }
}

// Round 2
// 194.775 us; speedup vs baseline: 1.1434x; 1.1434x over previous
//
#include <hip/hip_runtime.h>
#include <math.h>

// Problem dims (fixed by reference)
#define BATCH 2048
#define GIN 128
#define GH 128
#define NE 8
#define XIN 512
#define UU 512
#define NOUT 512
#define KAUG (NE * XIN)   // 4096
#define SPLIT 8
#define KS (KAUG / SPLIT) // 512 per k-split block == one expert block

typedef __attribute__((ext_vector_type(8))) short short8;   // 8 bf16 in 4 VGPRs
typedef __attribute__((ext_vector_type(4))) float f32x4;

__device__ inline unsigned short f2bf(float f) {
    unsigned u = __float_as_uint(f);
    u += 0x7fffu + ((u >> 16) & 1u);
    return (unsigned short)(u >> 16);
}

__device__ inline float elu1(float x) { return x > 0.f ? x : (expf(x) - 1.f); }

// ---------------------------------------------------------------------------
// Gating MLP v2: fp32 exact, latency-optimized.
// 512 blocks x 256 threads; block = 4 batch rows; K=128 split across 2 halves.
// ---------------------------------------------------------------------------
__global__ __launch_bounds__(256) void gating_kernel(
    const float* __restrict__ gin, const float* __restrict__ W0, const float* __restrict__ b0,
    const float* __restrict__ W1, const float* __restrict__ b1,
    const float* __restrict__ Wo, const float* __restrict__ bo,
    float* __restrict__ g)
{
    __shared__ float xs[4][128];
    __shared__ float hs[4][128];
    __shared__ float ps[2][4][128];
    __shared__ float lp[8][4][8];
    __shared__ float ls[4][8];

    const int t = threadIdx.x;
    const int c = t & 127;          // output feature
    const int h = t >> 7;           // k-half
    const int row0 = blockIdx.x * 4;

    // load 4 rows of gating input (512 floats, 2 per thread, coalesced)
    ((float*)xs)[t]       = gin[row0 * GIN + t];
    ((float*)xs)[t + 256] = gin[row0 * GIN + t + 256];
    __syncthreads();

    // ---- layer 0: xs @ W0 + b0, ELU -> hs ----
    {
        float acc0 = 0.f, acc1 = 0.f, acc2 = 0.f, acc3 = 0.f;
        const float* Wc = W0 + c;
        #pragma unroll 8
        for (int i = h * 64; i < h * 64 + 64; ++i) {
            float w = Wc[i * GH];
            acc0 += xs[0][i] * w; acc1 += xs[1][i] * w;
            acc2 += xs[2][i] * w; acc3 += xs[3][i] * w;
        }
        ps[h][0][c] = acc0; ps[h][1][c] = acc1; ps[h][2][c] = acc2; ps[h][3][c] = acc3;
    }
    __syncthreads();
    {
        int o = t;          // two outputs per thread
        int r = o >> 7, cc = o & 127;
        hs[r][cc] = elu1(ps[0][r][cc] + ps[1][r][cc] + b0[cc]);
        o = t + 256; r = o >> 7; cc = o & 127;
        hs[r][cc] = elu1(ps[0][r][cc] + ps[1][r][cc] + b0[cc]);
    }
    __syncthreads();

    // ---- layer 1: hs @ W1 + b1, ELU -> xs ----
    {
        float acc0 = 0.f, acc1 = 0.f, acc2 = 0.f, acc3 = 0.f;
        const float* Wc = W1 + c;
        #pragma unroll 8
        for (int i = h * 64; i < h * 64 + 64; ++i) {
            float w = Wc[i * GH];
            acc0 += hs[0][i] * w; acc1 += hs[1][i] * w;
            acc2 += hs[2][i] * w; acc3 += hs[3][i] * w;
        }
        ps[h][0][c] = acc0; ps[h][1][c] = acc1; ps[h][2][c] = acc2; ps[h][3][c] = acc3;
    }
    __syncthreads();
    {
        int o = t;
        int r = o >> 7, cc = o & 127;
        xs[r][cc] = elu1(ps[0][r][cc] + ps[1][r][cc] + b1[cc]);
        o = t + 256; r = o >> 7; cc = o & 127;
        xs[r][cc] = elu1(ps[0][r][cc] + ps[1][r][cc] + b1[cc]);
    }
    __syncthreads();

    // ---- layer 2: xs @ Wo + bo -> logits (4 rows x 8 experts), 8-way k-split
    {
        const int e = t & 7, r = (t >> 3) & 3, q = t >> 5;   // q in 0..7 splits K=128
        float s = 0.f;
        #pragma unroll
        for (int i = q * 16; i < q * 16 + 16; ++i) s += xs[r][i] * Wo[i * NE + e];
        lp[q][r][e] = s;
    }
    __syncthreads();
    if (t < 32) {
        const int r = t >> 3, e = t & 7;
        float s = bo[e];
        #pragma unroll
        for (int q = 0; q < 8; ++q) s += lp[q][r][e];
        ls[r][e] = s;
    }
    __syncthreads();
    if (t < 4) {
        float mx = ls[t][0];
        #pragma unroll
        for (int e = 1; e < 8; ++e) mx = fmaxf(mx, ls[t][e]);
        float s = 0.f, ex[8];
        #pragma unroll
        for (int e = 0; e < 8; ++e) { ex[e] = expf(ls[t][e] - mx); s += ex[e]; }
        float inv = 1.f / s;
        #pragma unroll
        for (int e = 0; e < 8; ++e) g[(row0 + t) * NE + e] = ex[e] * inv;
    }
}

// ---------------------------------------------------------------------------
// Convert the three alpha pools fp32 -> bf16 (contiguous in ws). 4 elems/thread.
// alpha natural layout (E,U,IN) row-major == the GEMM's B^T per-expert blocks.
// ---------------------------------------------------------------------------
__global__ __launch_bounds__(256) void convert_alpha_kernel(
    const float* __restrict__ a0, const float* __restrict__ a1, const float* __restrict__ a2,
    unsigned short* __restrict__ ab)
{
    const long long vi = (long long)(blockIdx.x * blockDim.x + threadIdx.x) * 4;
    const int a = (int)(vi >> 21);               // each alpha is 2^21 elements
    const int off = (int)(vi & ((1 << 21) - 1));
    const float* src = (a == 0) ? a0 : ((a == 1) ? a1 : a2);
    float4 v = *(const float4*)(src + off);
    union { unsigned short us[4]; uint2 u2; } p;
    p.us[0] = f2bf(v.x); p.us[1] = f2bf(v.y); p.us[2] = f2bf(v.z); p.us[3] = f2bf(v.w);
    *(uint2*)(ab + vi) = p.u2;
}

// ---------------------------------------------------------------------------
// Build augmented input, layout Z[e][b][i] = bf16(g[b,e] * x[b,i]).
// 4 elems/thread, 8 coalesced 8B stores.
// ---------------------------------------------------------------------------
__global__ __launch_bounds__(256) void zbuild0_kernel(
    const float* __restrict__ x, const float* __restrict__ g, unsigned short* __restrict__ Z)
{
    const int gid4 = (blockIdx.x * blockDim.x + threadIdx.x) * 4; // b*512 + i
    const int b = gid4 >> 9;
    const float4 xv = *(const float4*)(x + gid4);
    const float* gb = g + b * NE;
    #pragma unroll
    for (int e = 0; e < NE; ++e) {
        const float gv = gb[e];
        union { unsigned short us[4]; uint2 u2; } p;
        p.us[0] = f2bf(gv * xv.x); p.us[1] = f2bf(gv * xv.y);
        p.us[2] = f2bf(gv * xv.z); p.us[3] = f2bf(gv * xv.w);
        *(uint2*)(Z + (size_t)e * (BATCH * XIN) + gid4) = p.u2;
    }
}

// ---------------------------------------------------------------------------
// m97-style bf16 GEMM, 128x128 tile, BK=64, one expert per blockIdx.z.
// A: Z[e][2048][512].  Bw: alpha bf16 [e][n][i].  Cp: SPLIT x M x N fp32.
// ---------------------------------------------------------------------------
__global__ __launch_bounds__(256) void gemm_kernel(
    const unsigned short* __restrict__ A,
    const unsigned short* __restrict__ Bw,
    float* __restrict__ Cp)
{
    constexpr int M = BATCH, N = UU;
    __shared__ unsigned short As[128 * 64];
    __shared__ unsigned short Bs[128 * 64];
    const int t = threadIdx.x;
    const int n0 = blockIdx.x * 128;
    const int m0 = blockIdx.y * 128;
    const int e = blockIdx.z;
    const int wave = t >> 6, lane = t & 63;
    const int wm = (wave >> 1) * 64, wn = (wave & 1) * 64;

    f32x4 acc[4][4] = {};

    const int trow = t >> 3;        // 0..31
    const int tcol = (t & 7) * 8;   // element col within BK

    const unsigned short* Ae = A + ((size_t)e * M + m0) * 512;
    const unsigned short* Be = Bw + ((size_t)e * N + n0) * 512;

    for (int ki = 0; ki < KS; ki += 64) {
        __syncthreads();
        #pragma unroll
        for (int it = 0; it < 4; ++it) {
            const unsigned short* ga = Ae + (size_t)(trow + it * 32) * 512 + ki + tcol;
            __builtin_amdgcn_global_load_lds(
                (const __attribute__((address_space(1))) void*)ga,
                (__attribute__((address_space(3))) void*)(As + it * 2048 + t * 8), 16, 0, 0);
            const unsigned short* gb = Be + (size_t)(trow + it * 32) * 512 + ki + tcol;
            __builtin_amdgcn_global_load_lds(
                (const __attribute__((address_space(1))) void*)gb,
                (__attribute__((address_space(3))) void*)(Bs + it * 2048 + t * 8), 16, 0, 0);
        }
        __syncthreads();

        #pragma unroll
        for (int kk = 0; kk < 64; kk += 32) {
            short8 af[4], bfr[4];
            const int fr = lane & 15;
            const int fk = kk + (lane >> 4) * 8;
            #pragma unroll
            for (int i = 0; i < 4; ++i) af[i] = *(const short8*)(As + (wm + fr + i * 16) * 64 + fk);
            #pragma unroll
            for (int j = 0; j < 4; ++j) bfr[j] = *(const short8*)(Bs + (wn + fr + j * 16) * 64 + fk);
            #pragma unroll
            for (int i = 0; i < 4; ++i)
                #pragma unroll
                for (int j = 0; j < 4; ++j)
                    acc[i][j] = __builtin_amdgcn_mfma_f32_16x16x32_bf16(af[i], bfr[j], acc[i][j], 0, 0, 0);
        }
    }

    // epilogue: C/D mapping col=lane&15, row=(lane>>4)*4+reg  [m89-verified]
    float* Cb = Cp + (size_t)e * M * N;
    const int cl = lane & 15, rq = lane >> 4;
    #pragma unroll
    for (int i = 0; i < 4; ++i)
        #pragma unroll
        for (int j = 0; j < 4; ++j)
            #pragma unroll
            for (int r = 0; r < 4; ++r) {
                int row = m0 + wm + i * 16 + rq * 4 + r;
                int col = n0 + wn + j * 16 + cl;
                Cb[(size_t)row * N + col] = acc[i][j][r];
            }
}

// ---------------------------------------------------------------------------
// Reduce k-split partials + bias blend + ELU; emit next layer's Z (bf16,
// [e][b][u] layout) or final output (fp32). 4 elems/thread, vectorized.
// ---------------------------------------------------------------------------
__global__ __launch_bounds__(256) void reduce_kernel(
    const float* __restrict__ Cp, const float* __restrict__ g,
    const float* __restrict__ beta, unsigned short* __restrict__ Znext,
    float* __restrict__ out, int last)
{
    const int gid4 = (blockIdx.x * blockDim.x + threadIdx.x) * 4; // b*512 + u
    const int b = gid4 >> 9, u = gid4 & 511;
    float4 v = {0.f, 0.f, 0.f, 0.f};
    #pragma unroll
    for (int s = 0; s < SPLIT; ++s) {
        float4 p = *(const float4*)(Cp + (size_t)s * (BATCH * (size_t)UU) + gid4);
        v.x += p.x; v.y += p.y; v.z += p.z; v.w += p.w;
    }
    const float* gb = g + b * NE;
    float gv[NE];
    #pragma unroll
    for (int e = 0; e < NE; ++e) gv[e] = gb[e];
    #pragma unroll
    for (int e = 0; e < NE; ++e) {
        float4 bb = *(const float4*)(beta + e * UU + u);
        v.x += gv[e] * bb.x; v.y += gv[e] * bb.y; v.z += gv[e] * bb.z; v.w += gv[e] * bb.w;
    }
    if (last) {
        *(float4*)(out + gid4) = v;
    } else {
        v.x = elu1(v.x); v.y = elu1(v.y); v.z = elu1(v.z); v.w = elu1(v.w);
        #pragma unroll
        for (int e = 0; e < NE; ++e) {
            const float ge = gv[e];
            union { unsigned short us[4]; uint2 u2; } p;
            p.us[0] = f2bf(ge * v.x); p.us[1] = f2bf(ge * v.y);
            p.us[2] = f2bf(ge * v.z); p.us[3] = f2bf(ge * v.w);
            *(uint2*)(Znext + (size_t)e * (BATCH * UU) + gid4) = p.u2;
        }
    }
}

// ---------------------------------------------------------------------------
extern "C" void kernel_launch(void* const* d_in, const int* in_sizes, int n_in,
                              void* d_out, int out_size, void* d_ws, size_t ws_size,
                              hipStream_t stream)
{
    (void)in_sizes; (void)n_in; (void)out_size; (void)ws_size;
    const float* gin = (const float*)d_in[0];
    const float* xin = (const float*)d_in[1];
    const float* W0  = (const float*)d_in[2];
    const float* b0  = (const float*)d_in[3];
    const float* W1  = (const float*)d_in[4];
    const float* b1  = (const float*)d_in[5];
    const float* Wo  = (const float*)d_in[6];
    const float* bo  = (const float*)d_in[7];
    const float* alpha[3] = {(const float*)d_in[8],  (const float*)d_in[10], (const float*)d_in[12]};
    const float* beta[3]  = {(const float*)d_in[9],  (const float*)d_in[11], (const float*)d_in[13]};
    float* out = (float*)d_out;

    // ws layout (total ~63 MB)
    char* ws = (char*)d_ws;
    float* g = (float*)ws;                                   // 2048*8*4      = 64 KB
    size_t off = 65536;
    unsigned short* ab = (unsigned short*)(ws + off);        // 3 * 2^21 * 2  = 12.58 MB
    off += (size_t)3 * (1 << 21) * 2;
    unsigned short* Z = (unsigned short*)(ws + off);         // 2048*4096*2   = 16.78 MB
    off += (size_t)BATCH * KAUG * 2;
    float* Cp = (float*)(ws + off);                          // 8 * 2048*512*4 = 33.55 MB

    gating_kernel<<<BATCH / 4, 256, 0, stream>>>(gin, W0, b0, W1, b1, Wo, bo, g);
    convert_alpha_kernel<<<(3 * (1 << 21)) / 4 / 256, 256, 0, stream>>>(alpha[0], alpha[1], alpha[2], ab);
    zbuild0_kernel<<<(BATCH * XIN) / 4 / 256, 256, 0, stream>>>(xin, g, Z);

    for (int l = 0; l < 3; ++l) {
        gemm_kernel<<<dim3(UU / 128, BATCH / 128, SPLIT), 256, 0, stream>>>(
            Z, ab + (size_t)l * (1 << 21), Cp);
        reduce_kernel<<<(BATCH * UU) / 4 / 256, 256, 0, stream>>>(
            Cp, g, beta[l], Z, out, l == 2 ? 1 : 0);
    }
}

// Round 3
// 183.559 us; speedup vs baseline: 1.2132x; 1.0611x over previous
//
#include <hip/hip_runtime.h>
#include <math.h>

// Problem dims (fixed by reference)
#define BATCH 2048
#define GIN 128
#define GH 128
#define NE 8
#define XIN 512
#define UU 512
#define NPAIR 4           // expert pairs; each GEMM block handles 2 experts

typedef __attribute__((ext_vector_type(8))) short short8;   // 8 bf16 in 4 VGPRs
typedef __attribute__((ext_vector_type(4))) float f32x4;

__device__ inline unsigned short f2bf(float f) {
    unsigned u = __float_as_uint(f);
    u += 0x7fffu + ((u >> 16) & 1u);
    return (unsigned short)(u >> 16);
}

__device__ inline float elu1(float x) { return x > 0.f ? x : (expf(x) - 1.f); }

// ---------------------------------------------------------------------------
// Gating MLP: fp32 exact, latency-optimized.
// 512 blocks x 256 threads; block = 4 batch rows; K=128 split across 2 halves.
// ---------------------------------------------------------------------------
__global__ __launch_bounds__(256) void gating_kernel(
    const float* __restrict__ gin, const float* __restrict__ W0, const float* __restrict__ b0,
    const float* __restrict__ W1, const float* __restrict__ b1,
    const float* __restrict__ Wo, const float* __restrict__ bo,
    float* __restrict__ g)
{
    __shared__ float xs[4][128];
    __shared__ float hs[4][128];
    __shared__ float ps[2][4][128];
    __shared__ float lp[8][4][8];
    __shared__ float ls[4][8];

    const int t = threadIdx.x;
    const int c = t & 127;          // output feature
    const int h = t >> 7;           // k-half
    const int row0 = blockIdx.x * 4;

    ((float*)xs)[t]       = gin[row0 * GIN + t];
    ((float*)xs)[t + 256] = gin[row0 * GIN + t + 256];
    __syncthreads();

    {   // layer 0
        float acc0 = 0.f, acc1 = 0.f, acc2 = 0.f, acc3 = 0.f;
        const float* Wc = W0 + c;
        #pragma unroll 8
        for (int i = h * 64; i < h * 64 + 64; ++i) {
            float w = Wc[i * GH];
            acc0 += xs[0][i] * w; acc1 += xs[1][i] * w;
            acc2 += xs[2][i] * w; acc3 += xs[3][i] * w;
        }
        ps[h][0][c] = acc0; ps[h][1][c] = acc1; ps[h][2][c] = acc2; ps[h][3][c] = acc3;
    }
    __syncthreads();
    {
        int o = t, r = o >> 7, cc = o & 127;
        hs[r][cc] = elu1(ps[0][r][cc] + ps[1][r][cc] + b0[cc]);
        o = t + 256; r = o >> 7; cc = o & 127;
        hs[r][cc] = elu1(ps[0][r][cc] + ps[1][r][cc] + b0[cc]);
    }
    __syncthreads();

    {   // layer 1
        float acc0 = 0.f, acc1 = 0.f, acc2 = 0.f, acc3 = 0.f;
        const float* Wc = W1 + c;
        #pragma unroll 8
        for (int i = h * 64; i < h * 64 + 64; ++i) {
            float w = Wc[i * GH];
            acc0 += hs[0][i] * w; acc1 += hs[1][i] * w;
            acc2 += hs[2][i] * w; acc3 += hs[3][i] * w;
        }
        ps[h][0][c] = acc0; ps[h][1][c] = acc1; ps[h][2][c] = acc2; ps[h][3][c] = acc3;
    }
    __syncthreads();
    {
        int o = t, r = o >> 7, cc = o & 127;
        xs[r][cc] = elu1(ps[0][r][cc] + ps[1][r][cc] + b1[cc]);
        o = t + 256; r = o >> 7; cc = o & 127;
        xs[r][cc] = elu1(ps[0][r][cc] + ps[1][r][cc] + b1[cc]);
    }
    __syncthreads();

    {   // output layer, 8-way k-split
        const int e = t & 7, r = (t >> 3) & 3, q = t >> 5;
        float s = 0.f;
        #pragma unroll
        for (int i = q * 16; i < q * 16 + 16; ++i) s += xs[r][i] * Wo[i * NE + e];
        lp[q][r][e] = s;
    }
    __syncthreads();
    if (t < 32) {
        const int r = t >> 3, e = t & 7;
        float s = bo[e];
        #pragma unroll
        for (int q = 0; q < 8; ++q) s += lp[q][r][e];
        ls[r][e] = s;
    }
    __syncthreads();
    if (t < 4) {
        float mx = ls[t][0];
        #pragma unroll
        for (int e = 1; e < 8; ++e) mx = fmaxf(mx, ls[t][e]);
        float s = 0.f, ex[8];
        #pragma unroll
        for (int e = 0; e < 8; ++e) { ex[e] = expf(ls[t][e] - mx); s += ex[e]; }
        float inv = 1.f / s;
        #pragma unroll
        for (int e = 0; e < 8; ++e) g[(row0 + t) * NE + e] = ex[e] * inv;
    }
}

// ---------------------------------------------------------------------------
// Convert the three alpha pools fp32 -> bf16 (contiguous in ws). 4 elems/thread.
// ---------------------------------------------------------------------------
__global__ __launch_bounds__(256) void convert_alpha_kernel(
    const float* __restrict__ a0, const float* __restrict__ a1, const float* __restrict__ a2,
    unsigned short* __restrict__ ab)
{
    const long long vi = (long long)(blockIdx.x * blockDim.x + threadIdx.x) * 4;
    const int a = (int)(vi >> 21);               // each alpha is 2^21 elements
    const int off = (int)(vi & ((1 << 21) - 1));
    const float* src = (a == 0) ? a0 : ((a == 1) ? a1 : a2);
    float4 v = *(const float4*)(src + off);
    union { unsigned short us[4]; uint2 u2; } p;
    p.us[0] = f2bf(v.x); p.us[1] = f2bf(v.y); p.us[2] = f2bf(v.z); p.us[3] = f2bf(v.w);
    *(uint2*)(ab + vi) = p.u2;
}

// ---------------------------------------------------------------------------
// Cast expert input fp32 -> bf16 (plain X, 2048x512). 4 elems/thread.
// ---------------------------------------------------------------------------
__global__ __launch_bounds__(256) void xcast_kernel(
    const float* __restrict__ x, unsigned short* __restrict__ Xb)
{
    const int gid4 = (blockIdx.x * blockDim.x + threadIdx.x) * 4;
    const float4 v = *(const float4*)(x + gid4);
    union { unsigned short us[4]; uint2 u2; } p;
    p.us[0] = f2bf(v.x); p.us[1] = f2bf(v.y); p.us[2] = f2bf(v.z); p.us[3] = f2bf(v.w);
    *(uint2*)(Xb + gid4) = p.u2;
}

// ---------------------------------------------------------------------------
// MoE pair-merged GEMM: block tile 128(M) x 64(N) x 2 experts, BK=64, K=512.
// A: Xb (2048x512 bf16, shared by all experts). Bw: alpha bf16 [e][n][i].
// Epilogue scales acc_e by g[row,e] and writes one fused partial slab per pair:
// Cp[z][b][n] = g[b,2z]*P_{2z}[b,n] + g[b,2z+1]*P_{2z+1}[b,n].
// ---------------------------------------------------------------------------
__global__ __launch_bounds__(256) void moe_gemm_kernel(
    const unsigned short* __restrict__ A,
    const unsigned short* __restrict__ Bw,
    const float* __restrict__ g,
    float* __restrict__ Cp)
{
    constexpr int M = BATCH, N = UU, K = XIN;
    __shared__ unsigned short As[128 * 64];    // 16 KB
    __shared__ unsigned short Bs0[64 * 64];    // 8 KB
    __shared__ unsigned short Bs1[64 * 64];    // 8 KB
    __shared__ float gs[128][2];               // 1 KB

    const int t = threadIdx.x;
    const int n0 = blockIdx.x * 64;
    const int m0 = blockIdx.y * 128;
    const int z = blockIdx.z;
    const int e0 = 2 * z, e1 = 2 * z + 1;
    const int wave = t >> 6, lane = t & 63;
    const int wm = (wave >> 1) * 64;           // 0 or 64
    const int wn = (wave & 1) * 32;            // 0 or 32

    // stage g for this block's rows (read in epilogue only; barriers below cover it)
    if (t < 128) {
        gs[t][0] = g[(m0 + t) * NE + e0];
        gs[t][1] = g[(m0 + t) * NE + e1];
    }

    f32x4 acc0[4][2] = {};
    f32x4 acc1[4][2] = {};

    const int trow = t >> 3;        // 0..31
    const int tcol = (t & 7) * 8;   // element col within BK

    const unsigned short* Ae  = A  + (size_t)m0 * K;
    const unsigned short* Be0 = Bw + ((size_t)e0 * N + n0) * K;
    const unsigned short* Be1 = Bw + ((size_t)e1 * N + n0) * K;

    for (int ki = 0; ki < K; ki += 64) {
        __syncthreads();
        #pragma unroll
        for (int it = 0; it < 4; ++it) {
            const unsigned short* ga = Ae + (size_t)(trow + it * 32) * K + ki + tcol;
            __builtin_amdgcn_global_load_lds(
                (const __attribute__((address_space(1))) void*)ga,
                (__attribute__((address_space(3))) void*)(As + it * 2048 + t * 8), 16, 0, 0);
        }
        #pragma unroll
        for (int it = 0; it < 2; ++it) {
            const unsigned short* gb0 = Be0 + (size_t)(trow + it * 32) * K + ki + tcol;
            __builtin_amdgcn_global_load_lds(
                (const __attribute__((address_space(1))) void*)gb0,
                (__attribute__((address_space(3))) void*)(Bs0 + it * 2048 + t * 8), 16, 0, 0);
            const unsigned short* gb1 = Be1 + (size_t)(trow + it * 32) * K + ki + tcol;
            __builtin_amdgcn_global_load_lds(
                (const __attribute__((address_space(1))) void*)gb1,
                (__attribute__((address_space(3))) void*)(Bs1 + it * 2048 + t * 8), 16, 0, 0);
        }
        __syncthreads();

        #pragma unroll
        for (int kk = 0; kk < 64; kk += 32) {
            short8 af[4], bf0[2], bf1[2];
            const int fr = lane & 15;
            const int fk = kk + (lane >> 4) * 8;
            #pragma unroll
            for (int i = 0; i < 4; ++i) af[i] = *(const short8*)(As + (wm + fr + i * 16) * 64 + fk);
            #pragma unroll
            for (int j = 0; j < 2; ++j) {
                bf0[j] = *(const short8*)(Bs0 + (wn + fr + j * 16) * 64 + fk);
                bf1[j] = *(const short8*)(Bs1 + (wn + fr + j * 16) * 64 + fk);
            }
            #pragma unroll
            for (int i = 0; i < 4; ++i)
                #pragma unroll
                for (int j = 0; j < 2; ++j) {
                    acc0[i][j] = __builtin_amdgcn_mfma_f32_16x16x32_bf16(af[i], bf0[j], acc0[i][j], 0, 0, 0);
                    acc1[i][j] = __builtin_amdgcn_mfma_f32_16x16x32_bf16(af[i], bf1[j], acc1[i][j], 0, 0, 0);
                }
        }
    }

    // epilogue: C/D mapping col=lane&15, row=(lane>>4)*4+reg  [m89-verified]
    float* Cb = Cp + (size_t)z * M * N;
    const int cl = lane & 15, rq = lane >> 4;
    #pragma unroll
    for (int i = 0; i < 4; ++i)
        #pragma unroll
        for (int j = 0; j < 2; ++j)
            #pragma unroll
            for (int r = 0; r < 4; ++r) {
                const int rl = wm + i * 16 + rq * 4 + r;
                const int col = n0 + wn + j * 16 + cl;
                const float v = gs[rl][0] * acc0[i][j][r] + gs[rl][1] * acc1[i][j][r];
                Cb[(size_t)(m0 + rl) * N + col] = v;
            }
}

// ---------------------------------------------------------------------------
// Reduce 4 pair-slabs + bias blend + ELU; emit next layer's Xb (bf16) or
// final output (fp32). 4 elems/thread, vectorized.
// ---------------------------------------------------------------------------
__global__ __launch_bounds__(256) void reduce_kernel(
    const float* __restrict__ Cp, const float* __restrict__ g,
    const float* __restrict__ beta, unsigned short* __restrict__ Xnext,
    float* __restrict__ out, int last)
{
    const int gid4 = (blockIdx.x * blockDim.x + threadIdx.x) * 4; // b*512 + u
    const int b = gid4 >> 9, u = gid4 & 511;
    float4 v = {0.f, 0.f, 0.f, 0.f};
    #pragma unroll
    for (int s = 0; s < NPAIR; ++s) {
        float4 p = *(const float4*)(Cp + (size_t)s * (BATCH * (size_t)UU) + gid4);
        v.x += p.x; v.y += p.y; v.z += p.z; v.w += p.w;
    }
    const float* gb = g + b * NE;
    #pragma unroll
    for (int e = 0; e < NE; ++e) {
        const float ge = gb[e];
        float4 bb = *(const float4*)(beta + e * UU + u);
        v.x += ge * bb.x; v.y += ge * bb.y; v.z += ge * bb.z; v.w += ge * bb.w;
    }
    if (last) {
        *(float4*)(out + gid4) = v;
    } else {
        union { unsigned short us[4]; uint2 u2; } p;
        p.us[0] = f2bf(elu1(v.x)); p.us[1] = f2bf(elu1(v.y));
        p.us[2] = f2bf(elu1(v.z)); p.us[3] = f2bf(elu1(v.w));
        *(uint2*)(Xnext + gid4) = p.u2;
    }
}

// ---------------------------------------------------------------------------
extern "C" void kernel_launch(void* const* d_in, const int* in_sizes, int n_in,
                              void* d_out, int out_size, void* d_ws, size_t ws_size,
                              hipStream_t stream)
{
    (void)in_sizes; (void)n_in; (void)out_size; (void)ws_size;
    const float* gin = (const float*)d_in[0];
    const float* xin = (const float*)d_in[1];
    const float* W0  = (const float*)d_in[2];
    const float* b0  = (const float*)d_in[3];
    const float* W1  = (const float*)d_in[4];
    const float* b1  = (const float*)d_in[5];
    const float* Wo  = (const float*)d_in[6];
    const float* bo  = (const float*)d_in[7];
    const float* alpha[3] = {(const float*)d_in[8],  (const float*)d_in[10], (const float*)d_in[12]};
    const float* beta[3]  = {(const float*)d_in[9],  (const float*)d_in[11], (const float*)d_in[13]};
    float* out = (float*)d_out;

    // ws layout (~32 MB total)
    char* ws = (char*)d_ws;
    float* g = (float*)ws;                                   // 2048*8*4      = 64 KB
    size_t off = 65536;
    unsigned short* ab = (unsigned short*)(ws + off);        // 3 * 2^21 * 2  = 12.58 MB
    off += (size_t)3 * (1 << 21) * 2;
    unsigned short* Xb = (unsigned short*)(ws + off);        // 2048*512*2    = 2.1 MB
    off += (size_t)BATCH * XIN * 2;
    float* Cp = (float*)(ws + off);                          // 4 * 2048*512*4 = 16.8 MB

    gating_kernel<<<BATCH / 4, 256, 0, stream>>>(gin, W0, b0, W1, b1, Wo, bo, g);
    convert_alpha_kernel<<<(3 * (1 << 21)) / 4 / 256, 256, 0, stream>>>(alpha[0], alpha[1], alpha[2], ab);
    xcast_kernel<<<(BATCH * XIN) / 4 / 256, 256, 0, stream>>>(xin, Xb);

    for (int l = 0; l < 3; ++l) {
        moe_gemm_kernel<<<dim3(UU / 64, BATCH / 128, NPAIR), 256, 0, stream>>>(
            Xb, ab + (size_t)l * (1 << 21), g, Cp);
        reduce_kernel<<<(BATCH * UU) / 4 / 256, 256, 0, stream>>>(
            Cp, g, beta[l], Xb, out, l == 2 ? 1 : 0);
    }
}